// Round 16
// baseline (3170.879 us; speedup 1.0000x reference)
//
#include <hip/hip_runtime.h>
#include <hip/hip_bf16.h>
#include <math.h>

typedef unsigned short ushort_t;
typedef __attribute__((ext_vector_type(8))) short bf16x8;   // 8 bf16 (4 VGPRs)
typedef __attribute__((ext_vector_type(4))) float f32x4;

#define SCALE 0.03608439182435161f  // 1/sqrt(768)

__device__ __forceinline__ ushort_t f2bf(float f) {
  unsigned u = __float_as_uint(f);
  return (ushort_t)((u + 0x7FFFu + ((u >> 16) & 1u)) >> 16);  // RNE
}
__device__ __forceinline__ float bf2f(ushort_t h) {
  return __uint_as_float(((unsigned)h) << 16);
}

// split float4 -> hi/lo bf16 planes via v_cvt_pk. lo = exact fp32 residual of
// hi, so hi+lo precision (~2^-17 rel) holds regardless of hi rounding detail.
__device__ __forceinline__ void split4(float4 v, ushort_t* hh, ushort_t* ll) {
  __hip_bfloat162 h01 = __float22bfloat162_rn(make_float2(v.x, v.y));
  __hip_bfloat162 h23 = __float22bfloat162_rn(make_float2(v.z, v.w));
  unsigned u01 = *(unsigned*)&h01, u23 = *(unsigned*)&h23;
  float l0 = v.x - __uint_as_float((u01 & 0xFFFFu) << 16);
  float l1 = v.y - __uint_as_float(u01 & 0xFFFF0000u);
  float l2 = v.z - __uint_as_float((u23 & 0xFFFFu) << 16);
  float l3 = v.w - __uint_as_float(u23 & 0xFFFF0000u);
  __hip_bfloat162 g01 = __float22bfloat162_rn(make_float2(l0, l1));
  __hip_bfloat162 g23 = __float22bfloat162_rn(make_float2(l2, l3));
  *(unsigned*)&hh[0] = u01; *(unsigned*)&hh[2] = u23;
  *(unsigned*)&ll[0] = *(unsigned*)&g01; *(unsigned*)&ll[2] = *(unsigned*)&g23;
}

// ---------------------------------------------------------------------------
// mm: 128x128xK MFMA GEMM, NT form, bf16x3 triple product. Used for:
//   K0: H = W * R^T -> planar hi/lo planes in ws      (zMode=0)
//   K1: Z = X * H^T -> row-interleaved slots in d_out (zMode=1:
//       slot row r of s: ushort off = s*786432 + r*1536; hi [0,768), lo [768,1536))
// ---------------------------------------------------------------------------
struct MMP {
  const float* Af;  long aLd;
  const float* Bf;
  const ushort_t* Bhi; const ushort_t* Blo; long bLd;
  ushort_t* Chi; ushort_t* Clo; long cLd;
  int zMode;
  int K;
};

template <int BM>
__global__ __launch_bounds__(256) void mm(MMP P)
{
  __shared__ ushort_t lds[16384];   // Ah|Al|Bh|Bl, 4096 each (32 KB)
  ushort_t* Ah = lds;
  ushort_t* Al = lds + 4096;
  ushort_t* Bh = lds + 8192;
  ushort_t* Bl = lds + 12288;

  const int tid = threadIdx.x;
  int bx = blockIdx.x, by = blockIdx.y;
  {                                           // XCD-aware bijective swizzle
    int nwg = gridDim.x * gridDim.y;
    if ((nwg & 7) == 0) {
      int id = by * gridDim.x + bx;
      int q = nwg >> 3;
      int wid = (id & 7) * q + (id >> 3);
      bx = wid % gridDim.x;
      by = wid / gridDim.x;
    }
  }
  const int m0 = by * 128, n0 = bx * 128;

  const int lane = tid & 63;
  const int wave = tid >> 6;
  const int wm = (wave >> 1) * 64, wn = (wave & 1) * 64;
  const int lr = lane & 15, g = lane >> 4;

  f32x4 acc[4][4];
  #pragma unroll
  for (int i = 0; i < 4; ++i)
    #pragma unroll
    for (int j = 0; j < 4; ++j) {
      f32x4 zv = {0.f, 0.f, 0.f, 0.f};
      acc[i][j] = zv;
    }

  for (int k0 = 0; k0 < P.K; k0 += 32) {
    // stage A (fp32 -> hi/lo)
    #pragma unroll
    for (int rep = 0; rep < 4; ++rep) {
      int idx = tid + rep * 256;
      int row = idx >> 3, q = idx & 7;
      float4 v = *(const float4*)(P.Af + (long)(m0 + row) * P.aLd + k0 + q * 4);
      int off = row * 32 + (((q >> 1) ^ ((row >> 1) & 3)) << 3) + ((q & 1) << 2);
      ushort_t hh[4], ll[4];
      split4(v, hh, ll);
      *(uint2*)(Ah + off) = *(uint2*)hh;
      *(uint2*)(Al + off) = *(uint2*)ll;
    }
    // stage B
    if constexpr (BM == 0) {
      #pragma unroll
      for (int rep = 0; rep < 4; ++rep) {
        int idx = tid + rep * 256;
        int row = idx >> 3, q = idx & 7;
        float4 v = *(const float4*)(P.Bf + (long)(n0 + row) * P.bLd + k0 + q * 4);
        int off = row * 32 + (((q >> 1) ^ ((row >> 1) & 3)) << 3) + ((q & 1) << 2);
        ushort_t hh[4], ll[4];
        split4(v, hh, ll);
        *(uint2*)(Bh + off) = *(uint2*)hh;
        *(uint2*)(Bl + off) = *(uint2*)ll;
      }
    } else {
      #pragma unroll
      for (int rep = 0; rep < 2; ++rep) {
        int idx = tid + rep * 256;
        int row = idx >> 2, h8 = idx & 3;
        int off = row * 32 + ((h8 ^ ((row >> 1) & 3)) << 3);
        long gsrc = (long)(n0 + row) * P.bLd + k0 + h8 * 8;
        *(uint4*)(Bh + off) = *(const uint4*)(P.Bhi + gsrc);
        *(uint4*)(Bl + off) = *(const uint4*)(P.Blo + gsrc);
      }
    }
    __syncthreads();

    bf16x8 ar[4], br[4];
    #pragma unroll
    for (int i = 0; i < 4; ++i) {
      int row = wm + i * 16 + lr;
      ar[i] = *(const bf16x8*)(Ah + row * 32 + ((g ^ ((row >> 1) & 3)) << 3));
    }
    #pragma unroll
    for (int j = 0; j < 4; ++j) {
      int row = wn + j * 16 + lr;
      br[j] = *(const bf16x8*)(Bh + row * 32 + ((g ^ ((row >> 1) & 3)) << 3));
    }
    #pragma unroll
    for (int i = 0; i < 4; ++i)
      #pragma unroll
      for (int j = 0; j < 4; ++j)
        acc[i][j] = __builtin_amdgcn_mfma_f32_16x16x32_bf16(ar[i], br[j], acc[i][j], 0, 0, 0);
    #pragma unroll
    for (int j = 0; j < 4; ++j) {
      int row = wn + j * 16 + lr;
      bf16x8 blv = *(const bf16x8*)(Bl + row * 32 + ((g ^ ((row >> 1) & 3)) << 3));
      #pragma unroll
      for (int i = 0; i < 4; ++i)
        acc[i][j] = __builtin_amdgcn_mfma_f32_16x16x32_bf16(ar[i], blv, acc[i][j], 0, 0, 0);
    }
    #pragma unroll
    for (int i = 0; i < 4; ++i) {
      int row = wm + i * 16 + lr;
      bf16x8 alv = *(const bf16x8*)(Al + row * 32 + ((g ^ ((row >> 1) & 3)) << 3));
      #pragma unroll
      for (int j = 0; j < 4; ++j)
        acc[i][j] = __builtin_amdgcn_mfma_f32_16x16x32_bf16(alv, br[j], acc[i][j], 0, 0, 0);
    }
    __syncthreads();
  }

  // epilogue: hi/lo store. C/D layout: col = lane&15, row = (lane>>4)*4 + reg.
  #pragma unroll
  for (int i = 0; i < 4; ++i) {
    #pragma unroll
    for (int j = 0; j < 4; ++j) {
      int colG = n0 + wn + j * 16 + lr;
      #pragma unroll
      for (int r = 0; r < 4; ++r) {
        int rowG = m0 + wm + i * 16 + g * 4 + r;
        float v = acc[i][j][r];
        ushort_t hi = f2bf(v);
        ushort_t lo = f2bf(v - bf2f(hi));
        long off;
        if (P.zMode) off = (long)(rowG >> 9) * 786432 + (long)(rowG & 511) * 1536 + colG;
        else         off = (long)rowG * P.cLd + colG;
        P.Chi[off] = hi;        // zMode: Clo = Chi + 768 -> lo half of slot row
        P.Clo[off] = lo;
      }
    }
  }
}

// ---------------------------------------------------------------------------
// fsc10: fused scores+softmax, bf16x3 exact, 128-ROW tile, 2-phase.
// R15 root cause of fsc8/fsc9's spill: LDS was EXACTLY 80 KB, so 2 workgroups
// fit the 160 KB CU -> compiler budgeted for 2 wg/CU = 4 waves/SIMD = 128-reg
// cap -> acc[8][4] ate the whole cap, everything else spilled (610 MB scratch
// writes). Fix: pad LDS to 84 KB so only ONE workgroup fits -> 256-reg budget
// (acc in AGPR half + ~100 VGPRs, no spill). Body identical to fsc9 ->
// bit-identical results.
// ---------------------------------------------------------------------------
__global__ __launch_bounds__(512, 1) void fsc10(ushort_t* __restrict__ slots,
                                                const float* __restrict__ X)
{
  __shared__ ushort_t lds[43008];   // 84 KB (pad past 80 KB: forces 1 wg/CU)
  ushort_t* Bh = lds;
  ushort_t* Bl = lds + 16384;
  ushort_t* Ah = lds + 32768;
  ushort_t* Al = lds + 36864;
  float* redf = (float*)lds;        // overlay, used only after the k-loop
  float* reds = (float*)lds + 1536; // [128][12] each, 12 KB total

  const int id = blockIdx.x;
  const int c = id & 7, t0 = id >> 3;
  const int tile = t0 & 3;
  const int s = c + ((t0 >> 2) << 3);
  const int m0 = tile * 128;

  ushort_t* Az = slots + (long)s * 786432;       // slot rows: r*1536, hi|lo
  const float* Xf = X + (long)s * 393216;

  const int tid = threadIdx.x;
  const int lane = tid & 63;
  const int wave = tid >> 6;
  const int wn = wave * 64;
  const int lr = lane & 15, g = lane >> 4;

  // A staging: 512 tasks, 1/thread (hi AND lo for (row,h8))
  const int arow = tid >> 2, ah8 = tid & 3;
  const int aoff = arow * 32 + ((ah8 ^ ((arow >> 1) & 3)) << 3);
  const long asrc = (long)(m0 + arow) * 1536 + ah8 * 8;

  f32x4 acc[8][4];
  #pragma unroll
  for (int i = 0; i < 8; ++i)
    #pragma unroll
    for (int j = 0; j < 4; ++j) {
      f32x4 zv = {0.f, 0.f, 0.f, 0.f};
      acc[i][j] = zv;
    }

  for (int t = 0; t < 24; ++t) {
    const int k0 = t * 32;
    // ---- phase 1: stage (load -> split -> write) ----
    {
      uint4 avh = *(const uint4*)(Az + asrc + k0);
      uint4 avl = *(const uint4*)(Az + asrc + k0 + 768);
      *(uint4*)(Ah + aoff) = avh;
      *(uint4*)(Al + aoff) = avl;
      const float* xb = Xf + k0;
      #pragma unroll
      for (int rep = 0; rep < 8; ++rep) {
        int idx = tid + rep * 512;
        int row = idx >> 3, q = idx & 7;
        float4 v = *(const float4*)(xb + (long)row * 768 + q * 4);
        int off = row * 32 + (((q >> 1) ^ ((row >> 1) & 3)) << 3) + ((q & 1) << 2);
        ushort_t hh[4], ll[4];
        split4(v, hh, ll);
        *(uint2*)(Bh + off) = *(uint2*)hh;
        *(uint2*)(Bl + off) = *(uint2*)ll;
      }
    }
    __syncthreads();

    // ---- phase 2: compute (96 MFMA/wave) ----
    bf16x8 bhf[4], blf[4], arh[8];
    #pragma unroll
    for (int j = 0; j < 4; ++j) {
      int row = wn + j * 16 + lr;
      int off = row * 32 + ((g ^ ((row >> 1) & 3)) << 3);
      bhf[j] = *(const bf16x8*)(Bh + off);
      blf[j] = *(const bf16x8*)(Bl + off);
    }
    #pragma unroll
    for (int i = 0; i < 8; ++i) {
      int row = i * 16 + lr;
      arh[i] = *(const bf16x8*)(Ah + row * 32 + ((g ^ ((row >> 1) & 3)) << 3));
    }
    // pass 1: hh
    #pragma unroll
    for (int i = 0; i < 8; ++i)
      #pragma unroll
      for (int j = 0; j < 4; ++j)
        acc[i][j] = __builtin_amdgcn_mfma_f32_16x16x32_bf16(arh[i], bhf[j], acc[i][j], 0, 0, 0);
    // pass 2: hl
    #pragma unroll
    for (int i = 0; i < 8; ++i)
      #pragma unroll
      for (int j = 0; j < 4; ++j)
        acc[i][j] = __builtin_amdgcn_mfma_f32_16x16x32_bf16(arh[i], blf[j], acc[i][j], 0, 0, 0);
    // pass 3: lh (arl reloaded per-i)
    #pragma unroll
    for (int i = 0; i < 8; ++i) {
      int row = i * 16 + lr;
      bf16x8 arl = *(const bf16x8*)(Al + row * 32 + ((g ^ ((row >> 1) & 3)) << 3));
      #pragma unroll
      for (int j = 0; j < 4; ++j)
        acc[i][j] = __builtin_amdgcn_mfma_f32_16x16x32_bf16(arl, bhf[j], acc[i][j], 0, 0, 0);
    }
    __syncthreads();
  }

  // softmax over full rows (cross-wave via overlaid LDS)
  float mr[8][4];
  #pragma unroll
  for (int i = 0; i < 8; ++i)
    #pragma unroll
    for (int rg = 0; rg < 4; ++rg) {
      float mx = -3.0e38f;
      #pragma unroll
      for (int j = 0; j < 4; ++j) {
        acc[i][j][rg] *= SCALE;
        mx = fmaxf(mx, acc[i][j][rg]);
      }
      #pragma unroll
      for (int off = 8; off >= 1; off >>= 1) mx = fmaxf(mx, __shfl_xor(mx, off, 64));
      if (lr == 0) redf[(i * 16 + g * 4 + rg) * 12 + wave] = mx;
    }
  __syncthreads();
  #pragma unroll
  for (int i = 0; i < 8; ++i)
    #pragma unroll
    for (int rg = 0; rg < 4; ++rg) {
      int row = i * 16 + g * 4 + rg;
      float4 a = *(const float4*)&redf[row * 12];
      float4 b = *(const float4*)&redf[row * 12 + 4];
      mr[i][rg] = fmaxf(fmaxf(fmaxf(a.x, a.y), fmaxf(a.z, a.w)),
                        fmaxf(fmaxf(b.x, b.y), fmaxf(b.z, b.w)));
    }
  #pragma unroll
  for (int i = 0; i < 8; ++i)
    #pragma unroll
    for (int rg = 0; rg < 4; ++rg) {
      float sm = 0.f;
      #pragma unroll
      for (int j = 0; j < 4; ++j) {
        float e = __expf(acc[i][j][rg] - mr[i][rg]);
        acc[i][j][rg] = e;
        sm += e;
      }
      #pragma unroll
      for (int off = 8; off >= 1; off >>= 1) sm += __shfl_xor(sm, off, 64);
      if (lr == 0) reds[(i * 16 + g * 4 + rg) * 12 + wave] = sm;
    }
  __syncthreads();
  #pragma unroll
  for (int i = 0; i < 8; ++i)
    #pragma unroll
    for (int rg = 0; rg < 4; ++rg) {
      int row = i * 16 + g * 4 + rg;
      float4 a = *(const float4*)&reds[row * 12];
      float4 b = *(const float4*)&reds[row * 12 + 4];
      float inv = 1.0f / (a.x + a.y + a.z + a.w + b.x + b.y + b.z + b.w);
      #pragma unroll
      for (int j = 0; j < 4; ++j)
        Az[(long)(m0 + row) * 1536 + wn + j * 16 + lr] = f2bf(acc[i][j][rg] * inv);
    }
}

// ---------------------------------------------------------------------------
// pv: out_s = P * X_s. Block = 64 rows x ALL 768 cols of one s (8 blocks/s,
// XCD-affine). 768 thr = 12 waves; wave w owns cols [w*64, w*64+64).
// P (A, K=512) staged ONCE to swizzled LDS before any write. B-frags built
// from strided fp32 X loads + cvt_pk. Out fp32 overwrites own row slots.
// ---------------------------------------------------------------------------
__global__ __launch_bounds__(768) void pv(float* __restrict__ outp,
                                          const float* __restrict__ X)
{
  __shared__ ushort_t Pa[32768];   // 64 rows x 512, swizzled (64 KB)

  const int id = blockIdx.x;
  const int c = id & 7, r = id >> 3;
  const int tile = r & 7;
  const int s = c + ((r >> 3) << 3);
  const int m0 = tile * 64;

  const ushort_t* Ps = (const ushort_t*)outp + (long)s * 786432;
  const float* Xf = X + (long)s * 393216;

  const int tid = threadIdx.x;
  const int lane = tid & 63;
  const int wave = tid >> 6;
  const int wn = wave * 64;
  const int lr = lane & 15, g = lane >> 4;

  // stage P rows m0..m0+63 (4096 uint4 tasks)
  for (int idx = tid; idx < 4096; idx += 768) {
    int row = idx >> 6, h8 = idx & 63;
    int off = row * 512 + ((h8 ^ (row & 7)) << 3);
    *(uint4*)(Pa + off) = *(const uint4*)(Ps + (long)(m0 + row) * 1536 + h8 * 8);
  }
  __syncthreads();

  f32x4 acc[4][4];
  #pragma unroll
  for (int i = 0; i < 4; ++i)
    #pragma unroll
    for (int j = 0; j < 4; ++j) {
      f32x4 zv = {0.f, 0.f, 0.f, 0.f};
      acc[i][j] = zv;
    }

  for (int kk = 0; kk < 16; ++kk) {
    const int k0 = kk * 32;
    bf16x8 ar[4];
    #pragma unroll
    for (int i = 0; i < 4; ++i) {
      int row = i * 16 + lr;
      ar[i] = *(const bf16x8*)(Pa + row * 512 + (((kk * 4 + g) ^ (row & 7)) << 3));
    }
    #pragma unroll
    for (int j = 0; j < 4; ++j) {
      int col = wn + j * 16 + lr;
      float xv[8];
      #pragma unroll
      for (int i = 0; i < 8; ++i)
        xv[i] = Xf[(long)(k0 + g * 8 + i) * 768 + col];
      unsigned w[4];
      #pragma unroll
      for (int p = 0; p < 4; ++p) {
        __hip_bfloat162 hb = __float22bfloat162_rn(make_float2(xv[2 * p], xv[2 * p + 1]));
        w[p] = *(unsigned*)&hb;
      }
      bf16x8 bv = *(bf16x8*)w;
      #pragma unroll
      for (int i = 0; i < 4; ++i)
        acc[i][j] = __builtin_amdgcn_mfma_f32_16x16x32_bf16(ar[i], bv, acc[i][j], 0, 0, 0);
    }
  }

  float* Co = outp + (long)s * 393216;
  #pragma unroll
  for (int i = 0; i < 4; ++i)
    #pragma unroll
    for (int j = 0; j < 4; ++j) {
      int colG = wn + j * 16 + lr;
      #pragma unroll
      for (int rg = 0; rg < 4; ++rg) {
        int rowG = m0 + i * 16 + g * 4 + rg;
        Co[(long)rowG * 768 + colG] = acc[i][j][rg];
      }
    }
}

// ---------------------------------------------------------------------------
extern "C" void kernel_launch(void* const* d_in, const int* in_sizes, int n_in,
                              void* d_out, int out_size, void* d_ws, size_t ws_size,
                              hipStream_t stream) {
  const float* X = (const float*)d_in[0];
  const float* R = (const float*)d_in[1];  // rotation_params
  const float* W = (const float*)d_in[2];  // entangle_params

  // ws: only H hi/lo planes (768x768 each, 2.25 MB)
  ushort_t* Hhi = (ushort_t*)d_ws;
  ushort_t* Hlo = Hhi + 768 * 768;

  // K0: H = W * R^T (planar hi/lo in ws)
  {
    MMP p{};
    p.Af = W; p.aLd = 768;
    p.Bf = R; p.bLd = 768;
    p.Chi = Hhi; p.Clo = Hlo; p.cLd = 768; p.zMode = 0;
    p.K = 768;
    mm<0><<<dim3(6, 6), 256, 0, stream>>>(p);
  }
  // K1: Z = X * H^T -> row-interleaved slots filling all of d_out
  {
    MMP p{};
    p.Af = X; p.aLd = 768;
    p.Bhi = Hhi; p.Blo = Hlo; p.bLd = 768;
    p.Chi = (ushort_t*)d_out;
    p.Clo = (ushort_t*)d_out + 768;   // lo half of each 1536-ushort row slot
    p.zMode = 1;
    p.K = 768;
    mm<1><<<dim3(6, 2048), 256, 0, stream>>>(p);
  }
  // K2: fused scores+softmax -> P into slots (128-row tiles, 84KB LDS pad)
  fsc10<<<dim3(2048), 512, 0, stream>>>((ushort_t*)d_out, X);
  // K3: out = P * V, overwriting slots with final fp32 (all s)
  pv<<<dim3(4096), 768, 0, stream>>>((float*)d_out, X);
}

// Round 17
// 2773.024 us; speedup vs baseline: 1.1435x; 1.1435x over previous
//
#include <hip/hip_runtime.h>
#include <hip/hip_bf16.h>
#include <math.h>

typedef unsigned short ushort_t;
typedef __attribute__((ext_vector_type(8))) short bf16x8;   // 8 bf16 (4 VGPRs)
typedef __attribute__((ext_vector_type(4))) float f32x4;

#define SCALE 0.03608439182435161f  // 1/sqrt(768)

__device__ __forceinline__ ushort_t f2bf(float f) {
  unsigned u = __float_as_uint(f);
  return (ushort_t)((u + 0x7FFFu + ((u >> 16) & 1u)) >> 16);  // RNE
}
__device__ __forceinline__ float bf2f(ushort_t h) {
  return __uint_as_float(((unsigned)h) << 16);
}

// split float4 -> hi/lo bf16 planes via v_cvt_pk. lo = exact fp32 residual of
// hi, so hi+lo precision (~2^-17 rel) holds regardless of hi rounding detail.
__device__ __forceinline__ void split4(float4 v, ushort_t* hh, ushort_t* ll) {
  __hip_bfloat162 h01 = __float22bfloat162_rn(make_float2(v.x, v.y));
  __hip_bfloat162 h23 = __float22bfloat162_rn(make_float2(v.z, v.w));
  unsigned u01 = *(unsigned*)&h01, u23 = *(unsigned*)&h23;
  float l0 = v.x - __uint_as_float((u01 & 0xFFFFu) << 16);
  float l1 = v.y - __uint_as_float(u01 & 0xFFFF0000u);
  float l2 = v.z - __uint_as_float((u23 & 0xFFFFu) << 16);
  float l3 = v.w - __uint_as_float(u23 & 0xFFFF0000u);
  __hip_bfloat162 g01 = __float22bfloat162_rn(make_float2(l0, l1));
  __hip_bfloat162 g23 = __float22bfloat162_rn(make_float2(l2, l3));
  *(unsigned*)&hh[0] = u01; *(unsigned*)&hh[2] = u23;
  *(unsigned*)&ll[0] = *(unsigned*)&g01; *(unsigned*)&ll[2] = *(unsigned*)&g23;
}

// ---------------------------------------------------------------------------
// mm: 128x128xK MFMA GEMM, NT form, bf16x3 triple product. Used for:
//   K0: H = W * R^T -> planar hi/lo planes in ws      (zMode=0)
//   K1: Z = X * H^T -> row-interleaved slots in d_out (zMode=1:
//       slot row r of s: ushort off = s*786432 + r*1536; hi [0,768), lo [768,1536))
// ---------------------------------------------------------------------------
struct MMP {
  const float* Af;  long aLd;
  const float* Bf;
  const ushort_t* Bhi; const ushort_t* Blo; long bLd;
  ushort_t* Chi; ushort_t* Clo; long cLd;
  int zMode;
  int K;
};

template <int BM>
__global__ __launch_bounds__(256) void mm(MMP P)
{
  __shared__ ushort_t lds[16384];   // Ah|Al|Bh|Bl, 4096 each (32 KB)
  ushort_t* Ah = lds;
  ushort_t* Al = lds + 4096;
  ushort_t* Bh = lds + 8192;
  ushort_t* Bl = lds + 12288;

  const int tid = threadIdx.x;
  int bx = blockIdx.x, by = blockIdx.y;
  {                                           // XCD-aware bijective swizzle
    int nwg = gridDim.x * gridDim.y;
    if ((nwg & 7) == 0) {
      int id = by * gridDim.x + bx;
      int q = nwg >> 3;
      int wid = (id & 7) * q + (id >> 3);
      bx = wid % gridDim.x;
      by = wid / gridDim.x;
    }
  }
  const int m0 = by * 128, n0 = bx * 128;

  const int lane = tid & 63;
  const int wave = tid >> 6;
  const int wm = (wave >> 1) * 64, wn = (wave & 1) * 64;
  const int lr = lane & 15, g = lane >> 4;

  f32x4 acc[4][4];
  #pragma unroll
  for (int i = 0; i < 4; ++i)
    #pragma unroll
    for (int j = 0; j < 4; ++j) {
      f32x4 zv = {0.f, 0.f, 0.f, 0.f};
      acc[i][j] = zv;
    }

  for (int k0 = 0; k0 < P.K; k0 += 32) {
    // stage A (fp32 -> hi/lo)
    #pragma unroll
    for (int rep = 0; rep < 4; ++rep) {
      int idx = tid + rep * 256;
      int row = idx >> 3, q = idx & 7;
      float4 v = *(const float4*)(P.Af + (long)(m0 + row) * P.aLd + k0 + q * 4);
      int off = row * 32 + (((q >> 1) ^ ((row >> 1) & 3)) << 3) + ((q & 1) << 2);
      ushort_t hh[4], ll[4];
      split4(v, hh, ll);
      *(uint2*)(Ah + off) = *(uint2*)hh;
      *(uint2*)(Al + off) = *(uint2*)ll;
    }
    // stage B
    if constexpr (BM == 0) {
      #pragma unroll
      for (int rep = 0; rep < 4; ++rep) {
        int idx = tid + rep * 256;
        int row = idx >> 3, q = idx & 7;
        float4 v = *(const float4*)(P.Bf + (long)(n0 + row) * P.bLd + k0 + q * 4);
        int off = row * 32 + (((q >> 1) ^ ((row >> 1) & 3)) << 3) + ((q & 1) << 2);
        ushort_t hh[4], ll[4];
        split4(v, hh, ll);
        *(uint2*)(Bh + off) = *(uint2*)hh;
        *(uint2*)(Bl + off) = *(uint2*)ll;
      }
    } else {
      #pragma unroll
      for (int rep = 0; rep < 2; ++rep) {
        int idx = tid + rep * 256;
        int row = idx >> 2, h8 = idx & 3;
        int off = row * 32 + ((h8 ^ ((row >> 1) & 3)) << 3);
        long gsrc = (long)(n0 + row) * P.bLd + k0 + h8 * 8;
        *(uint4*)(Bh + off) = *(const uint4*)(P.Bhi + gsrc);
        *(uint4*)(Bl + off) = *(const uint4*)(P.Blo + gsrc);
      }
    }
    __syncthreads();

    bf16x8 ar[4], br[4];
    #pragma unroll
    for (int i = 0; i < 4; ++i) {
      int row = wm + i * 16 + lr;
      ar[i] = *(const bf16x8*)(Ah + row * 32 + ((g ^ ((row >> 1) & 3)) << 3));
    }
    #pragma unroll
    for (int j = 0; j < 4; ++j) {
      int row = wn + j * 16 + lr;
      br[j] = *(const bf16x8*)(Bh + row * 32 + ((g ^ ((row >> 1) & 3)) << 3));
    }
    #pragma unroll
    for (int i = 0; i < 4; ++i)
      #pragma unroll
      for (int j = 0; j < 4; ++j)
        acc[i][j] = __builtin_amdgcn_mfma_f32_16x16x32_bf16(ar[i], br[j], acc[i][j], 0, 0, 0);
    #pragma unroll
    for (int j = 0; j < 4; ++j) {
      int row = wn + j * 16 + lr;
      bf16x8 blv = *(const bf16x8*)(Bl + row * 32 + ((g ^ ((row >> 1) & 3)) << 3));
      #pragma unroll
      for (int i = 0; i < 4; ++i)
        acc[i][j] = __builtin_amdgcn_mfma_f32_16x16x32_bf16(ar[i], blv, acc[i][j], 0, 0, 0);
    }
    #pragma unroll
    for (int i = 0; i < 4; ++i) {
      int row = wm + i * 16 + lr;
      bf16x8 alv = *(const bf16x8*)(Al + row * 32 + ((g ^ ((row >> 1) & 3)) << 3));
      #pragma unroll
      for (int j = 0; j < 4; ++j)
        acc[i][j] = __builtin_amdgcn_mfma_f32_16x16x32_bf16(alv, br[j], acc[i][j], 0, 0, 0);
    }
    __syncthreads();
  }

  // epilogue: hi/lo store. C/D layout: col = lane&15, row = (lane>>4)*4 + reg.
  #pragma unroll
  for (int i = 0; i < 4; ++i) {
    #pragma unroll
    for (int j = 0; j < 4; ++j) {
      int colG = n0 + wn + j * 16 + lr;
      #pragma unroll
      for (int r = 0; r < 4; ++r) {
        int rowG = m0 + wm + i * 16 + g * 4 + r;
        float v = acc[i][j][r];
        ushort_t hi = f2bf(v);
        ushort_t lo = f2bf(v - bf2f(hi));
        long off;
        if (P.zMode) off = (long)(rowG >> 9) * 786432 + (long)(rowG & 511) * 1536 + colG;
        else         off = (long)rowG * P.cLd + colG;
        P.Chi[off] = hi;        // zMode: Clo = Chi + 768 -> lo half of slot row
        P.Clo[off] = lo;
      }
    }
  }
}

// ---------------------------------------------------------------------------
// fpv: fsc6 (proven R11 structure, bit-identical) + FUSED PV phase.
// Block = 64 rows x 512 cols of one s (8 blocks/s, XCD-affine). 512 thr =
// 8 waves. After the k-loop + softmax, P is written to LDS (dead B0 region,
// pv's swizzled layout) instead of HBM; then the pv kk-loop runs in-block
// (P from LDS, X from L2-warm global) and writes fp32 out IN-PLACE over the
// block's own Z rows (only this block reads those rows -> race-free).
// PV cols split into 2 groups of 48/wave (acc2[4][3]=48 regs) to keep peak
// VGPR ~ fsc6's (~104) -- below the 128 cliff seen in fsc8/9/10.
// Eliminates: P HBM write (262MB) + read (262MB) + the pv dispatch.
// Accumulation order per output element identical to standalone pv ->
// bit-identical results.
// ---------------------------------------------------------------------------
__global__ __launch_bounds__(512, 1) void fpv(ushort_t* __restrict__ slots,
                                              const float* __restrict__ X)
{
  __shared__ ushort_t lds[73728];   // 144 KB: A0|A1|B0|B1 (fsc6 layout)
  float* redf = (float*)lds;        // overlay after k-loop (A region)
  float* reds = (float*)lds + 768;
  ushort_t* Pl = lds + 8192;        // P region = dead B0: 32768 ushorts = 64 KB

  const int id = blockIdx.x;
  const int c = id & 7, r = id >> 3;
  const int tile = r & 7;
  const int s = c + ((r >> 3) << 3);
  const int m0 = tile * 64;

  ushort_t* Az = slots + (long)s * 786432;       // slot rows: r*1536, hi|lo
  const float* Xf = X + (long)s * 393216;

  const int tid = threadIdx.x;
  const int lane = tid & 63;
  const int wave = tid >> 6;
  const int wn = wave * 64;
  const int lr = lane & 15, g = lane >> 4;

  // A staging: 512 uint4 tasks (tid<256: hi plane, else lo plane)
  const int ae = tid & 255;
  const int arow = ae >> 2, ah8 = ae & 3;
  const int aoff = arow * 32 + ((ah8 ^ ((arow >> 1) & 3)) << 3);
  const long asrc = (long)(m0 + arow) * 1536 + ah8 * 8 + (tid < 256 ? 0 : 768);
  const int adst = aoff + (tid < 256 ? 0 : 2048);

  f32x4 acc[4][4];
  #pragma unroll
  for (int i = 0; i < 4; ++i)
    #pragma unroll
    for (int j = 0; j < 4; ++j) {
      f32x4 zv = {0.f, 0.f, 0.f, 0.f};
      acc[i][j] = zv;
    }

  float4 bv0, bv1, bv2, bv3, bv4, bv5, bv6, bv7;   // in-flight B tile (32 VGPR)
  uint4 av;                                        // in-flight A quarter-row

#define FSC_LOAD(K0)                                                         \
  do {                                                                       \
    av = *(const uint4*)(Az + asrc + (K0));                                  \
    const float* xb = Xf + (K0);                                             \
    bv0 = *(const float4*)(xb + (long)((tid + 0 * 512) >> 3) * 768 + ((tid + 0 * 512) & 7) * 4); \
    bv1 = *(const float4*)(xb + (long)((tid + 1 * 512) >> 3) * 768 + ((tid + 1 * 512) & 7) * 4); \
    bv2 = *(const float4*)(xb + (long)((tid + 2 * 512) >> 3) * 768 + ((tid + 2 * 512) & 7) * 4); \
    bv3 = *(const float4*)(xb + (long)((tid + 3 * 512) >> 3) * 768 + ((tid + 3 * 512) & 7) * 4); \
    bv4 = *(const float4*)(xb + (long)((tid + 4 * 512) >> 3) * 768 + ((tid + 4 * 512) & 7) * 4); \
    bv5 = *(const float4*)(xb + (long)((tid + 5 * 512) >> 3) * 768 + ((tid + 5 * 512) & 7) * 4); \
    bv6 = *(const float4*)(xb + (long)((tid + 6 * 512) >> 3) * 768 + ((tid + 6 * 512) & 7) * 4); \
    bv7 = *(const float4*)(xb + (long)((tid + 7 * 512) >> 3) * 768 + ((tid + 7 * 512) & 7) * 4); \
  } while (0)

#define FSC_WR1(BH, BL, BV, REP)                                             \
  do {                                                                       \
    int idx = tid + (REP) * 512;                                             \
    int row = idx >> 3, q = idx & 7;                                         \
    int off = row * 32 + (((q >> 1) ^ ((row >> 1) & 3)) << 3) + ((q & 1) << 2); \
    ushort_t hh[4], ll[4];                                                   \
    split4(BV, hh, ll);                                                      \
    *(uint2*)((BH) + off) = *(uint2*)hh;                                     \
    *(uint2*)((BL) + off) = *(uint2*)ll;                                     \
  } while (0)

#define FSC_WRITE(B)                                                         \
  do {                                                                       \
    ushort_t* Ab = lds + (B) * 4096;                                         \
    ushort_t* Bhw = lds + 8192 + (B) * 32768;                                \
    ushort_t* Blw = Bhw + 16384;                                             \
    *(uint4*)(Ab + adst) = av;                                               \
    FSC_WR1(Bhw, Blw, bv0, 0); FSC_WR1(Bhw, Blw, bv1, 1);                    \
    FSC_WR1(Bhw, Blw, bv2, 2); FSC_WR1(Bhw, Blw, bv3, 3);                    \
    FSC_WR1(Bhw, Blw, bv4, 4); FSC_WR1(Bhw, Blw, bv5, 5);                    \
    FSC_WR1(Bhw, Blw, bv6, 6); FSC_WR1(Bhw, Blw, bv7, 7);                    \
  } while (0)

  FSC_LOAD(0);
  FSC_WRITE(0);
  __syncthreads();

  for (int t = 0; t < 24; ++t) {
    const int cb = t & 1;
    if (t < 23) FSC_LOAD((t + 1) * 32);
    // Pin loads above compute (R10: compiler sinks them into FSC_WRITE).
    __builtin_amdgcn_sched_barrier(0);

    const ushort_t* Ab = lds + cb * 4096;
    const ushort_t* Bh = lds + 8192 + cb * 32768;
    const ushort_t* Bl = Bh + 16384;

    bf16x8 arh[4], arl[4], bh[4], bl[4];
    #pragma unroll
    for (int i = 0; i < 4; ++i) {
      int row = i * 16 + lr;
      int off = row * 32 + ((g ^ ((row >> 1) & 3)) << 3);
      arh[i] = *(const bf16x8*)(Ab + off);
      arl[i] = *(const bf16x8*)(Ab + 2048 + off);
    }
    #pragma unroll
    for (int j = 0; j < 4; ++j) {
      int row = wn + j * 16 + lr;
      int off = row * 32 + ((g ^ ((row >> 1) & 3)) << 3);
      bh[j] = *(const bf16x8*)(Bh + off);
      bl[j] = *(const bf16x8*)(Bl + off);
    }
    #pragma unroll
    for (int i = 0; i < 4; ++i)
      #pragma unroll
      for (int j = 0; j < 4; ++j)
        acc[i][j] = __builtin_amdgcn_mfma_f32_16x16x32_bf16(arh[i], bh[j], acc[i][j], 0, 0, 0);
    #pragma unroll
    for (int i = 0; i < 4; ++i)
      #pragma unroll
      for (int j = 0; j < 4; ++j)
        acc[i][j] = __builtin_amdgcn_mfma_f32_16x16x32_bf16(arh[i], bl[j], acc[i][j], 0, 0, 0);
    #pragma unroll
    for (int i = 0; i < 4; ++i)
      #pragma unroll
      for (int j = 0; j < 4; ++j)
        acc[i][j] = __builtin_amdgcn_mfma_f32_16x16x32_bf16(arl[i], bh[j], acc[i][j], 0, 0, 0);

    if (t < 23) FSC_WRITE(1 - cb);
    __syncthreads();
  }

  // ---- softmax over full rows (cross-wave via overlaid LDS) ----
  float mr[4][4];
  #pragma unroll
  for (int i = 0; i < 4; ++i)
    #pragma unroll
    for (int rg = 0; rg < 4; ++rg) {
      float mx = -3.0e38f;
      #pragma unroll
      for (int j = 0; j < 4; ++j) {
        acc[i][j][rg] *= SCALE;
        mx = fmaxf(mx, acc[i][j][rg]);
      }
      #pragma unroll
      for (int off = 8; off >= 1; off >>= 1) mx = fmaxf(mx, __shfl_xor(mx, off, 64));
      if (lr == 0) redf[(i * 16 + g * 4 + rg) * 12 + wave] = mx;
    }
  __syncthreads();
  #pragma unroll
  for (int i = 0; i < 4; ++i)
    #pragma unroll
    for (int rg = 0; rg < 4; ++rg) {
      int row = i * 16 + g * 4 + rg;
      float4 a = *(const float4*)&redf[row * 12];
      float4 b = *(const float4*)&redf[row * 12 + 4];
      mr[i][rg] = fmaxf(fmaxf(fmaxf(a.x, a.y), fmaxf(a.z, a.w)),
                        fmaxf(fmaxf(b.x, b.y), fmaxf(b.z, b.w)));
    }
  #pragma unroll
  for (int i = 0; i < 4; ++i)
    #pragma unroll
    for (int rg = 0; rg < 4; ++rg) {
      float sm = 0.f;
      #pragma unroll
      for (int j = 0; j < 4; ++j) {
        float e = __expf(acc[i][j][rg] - mr[i][rg]);
        acc[i][j][rg] = e;
        sm += e;
      }
      #pragma unroll
      for (int off = 8; off >= 1; off >>= 1) sm += __shfl_xor(sm, off, 64);
      if (lr == 0) reds[(i * 16 + g * 4 + rg) * 12 + wave] = sm;
    }
  __syncthreads();
  // ---- write P (bf16) into LDS P-region, pv's swizzled layout ----
  #pragma unroll
  for (int i = 0; i < 4; ++i)
    #pragma unroll
    for (int rg = 0; rg < 4; ++rg) {
      int row = i * 16 + g * 4 + rg;
      float4 a = *(const float4*)&reds[row * 12];
      float4 b = *(const float4*)&reds[row * 12 + 4];
      float inv = 1.0f / (a.x + a.y + a.z + a.w + b.x + b.y + b.z + b.w);
      #pragma unroll
      for (int j = 0; j < 4; ++j) {
        int col = wn + j * 16 + lr;
        Pl[row * 512 + (((col >> 3) ^ (row & 7)) << 3) + (col & 7)] =
            f2bf(acc[i][j][rg] * inv);
      }
    }
  __syncthreads();

  // ---- PV phase: out rows m0..m0+63 = P(64x512, LDS) * X_s(512x768) ----
  // 2 col-groups of 48 per wave; per-output accumulation order == old pv.
  float* Co = (float*)slots + (long)s * 393216;
  #pragma unroll
  for (int cg = 0; cg < 2; ++cg) {
    const int cbase = wave * 96 + cg * 48;
    f32x4 acc2[4][3];
    #pragma unroll
    for (int i = 0; i < 4; ++i)
      #pragma unroll
      for (int j = 0; j < 3; ++j) {
        f32x4 zv = {0.f, 0.f, 0.f, 0.f};
        acc2[i][j] = zv;
      }
    for (int kk = 0; kk < 16; ++kk) {
      bf16x8 pa[4];
      #pragma unroll
      for (int i = 0; i < 4; ++i) {
        int row = i * 16 + lr;
        pa[i] = *(const bf16x8*)(Pl + row * 512 + (((kk * 4 + g) ^ (row & 7)) << 3));
      }
      #pragma unroll
      for (int j = 0; j < 3; ++j) {
        int col = cbase + j * 16 + lr;
        float xv[8];
        #pragma unroll
        for (int ii = 0; ii < 8; ++ii)
          xv[ii] = Xf[(long)(kk * 32 + g * 8 + ii) * 768 + col];
        unsigned w[4];
        #pragma unroll
        for (int p = 0; p < 4; ++p) {
          __hip_bfloat162 hb = __float22bfloat162_rn(make_float2(xv[2 * p], xv[2 * p + 1]));
          w[p] = *(unsigned*)&hb;
        }
        bf16x8 bv = *(bf16x8*)w;
        #pragma unroll
        for (int i = 0; i < 4; ++i)
          acc2[i][j] = __builtin_amdgcn_mfma_f32_16x16x32_bf16(pa[i], bv, acc2[i][j], 0, 0, 0);
      }
    }
    // epilogue: fp32 out over this block's own rows (in-place over Z slots)
    #pragma unroll
    for (int i = 0; i < 4; ++i)
      #pragma unroll
      for (int j = 0; j < 3; ++j) {
        int colG = cbase + j * 16 + lr;
        #pragma unroll
        for (int rg = 0; rg < 4; ++rg) {
          int rowG = m0 + i * 16 + g * 4 + rg;
          Co[(long)rowG * 768 + colG] = acc2[i][j][rg];
        }
      }
  }
}

// ---------------------------------------------------------------------------
extern "C" void kernel_launch(void* const* d_in, const int* in_sizes, int n_in,
                              void* d_out, int out_size, void* d_ws, size_t ws_size,
                              hipStream_t stream) {
  const float* X = (const float*)d_in[0];
  const float* R = (const float*)d_in[1];  // rotation_params
  const float* W = (const float*)d_in[2];  // entangle_params

  // ws: only H hi/lo planes (768x768 each, 2.25 MB)
  ushort_t* Hhi = (ushort_t*)d_ws;
  ushort_t* Hlo = Hhi + 768 * 768;

  // K0: H = W * R^T (planar hi/lo in ws)
  {
    MMP p{};
    p.Af = W; p.aLd = 768;
    p.Bf = R; p.bLd = 768;
    p.Chi = Hhi; p.Clo = Hlo; p.cLd = 768; p.zMode = 0;
    p.K = 768;
    mm<0><<<dim3(6, 6), 256, 0, stream>>>(p);
  }
  // K1: Z = X * H^T -> row-interleaved slots filling all of d_out
  {
    MMP p{};
    p.Af = X; p.aLd = 768;
    p.Bhi = Hhi; p.Blo = Hlo; p.bLd = 768;
    p.Chi = (ushort_t*)d_out;
    p.Clo = (ushort_t*)d_out + 768;   // lo half of each 1536-ushort row slot
    p.zMode = 1;
    p.K = 768;
    mm<1><<<dim3(6, 2048), 256, 0, stream>>>(p);
  }
  // K2: fused scores+softmax+PV -> fp32 out in-place (P never touches HBM)
  fpv<<<dim3(4096), 512, 0, stream>>>((ushort_t*)d_out, X);
}